// Round 1
// baseline (61.699 us; speedup 1.0000x reference)
//
#include <hip/hip_runtime.h>

// BeliefModuleOld: B=1e6, T=5, NTYPES=2, D=6
// in[0]: visible_treats [B,5,2,6] f32  (contiguous, 60 floats / batch)
// in[1]: vision         [B,5]     i32
// out:   [B,2,6] f32

__global__ __launch_bounds__(256) void belief_kernel(
    const float4* __restrict__ vt4,   // visible_treats as float4 (15 per batch)
    const int*    __restrict__ vision,
    float4*       __restrict__ out4,  // output as float4 (3 per batch)
    int B)
{
    int b = blockIdx.x * blockDim.x + threadIdx.x;
    if (b >= B) return;

    // Load 60 floats = 15 float4
    const float4* p = vt4 + (size_t)b * 15;
    float f[60];
#pragma unroll
    for (int k = 0; k < 15; ++k) {
        float4 r = p[k];
        f[4*k + 0] = r.x;
        f[4*k + 1] = r.y;
        f[4*k + 2] = r.z;
        f[4*k + 3] = r.w;
    }

    const int* vp = vision + (size_t)b * 5;
    int v[5];
#pragma unroll
    for (int t = 0; t < 5; ++t) v[t] = vp[t];

    // o[tt*6 + d], defaults [0,0,0,0,0,1]
    float o[12];
#pragma unroll
    for (int tt = 0; tt < 2; ++tt) {
        o[tt*6 + 0] = 0.f; o[tt*6 + 1] = 0.f; o[tt*6 + 2] = 0.f;
        o[tt*6 + 3] = 0.f; o[tt*6 + 4] = 0.f; o[tt*6 + 5] = 1.f;
    }

#pragma unroll
    for (int t = 0; t < 5; ++t) {
#pragma unroll
        for (int tt = 0; tt < 2; ++tt) {
            const int base = t*12 + tt*6;   // float index of vt[b,t,tt,0]
            float m = f[base + 0];
            m = fmaxf(m, f[base + 1]);
            m = fmaxf(m, f[base + 2]);
            m = fmaxf(m, f[base + 3]);
            m = fmaxf(m, f[base + 4]);
            bool valid = (v[t] != 0) && (m > 0.5f);
            // ascending t + overwrite == "last valid t wins"
            if (valid) {
#pragma unroll
                for (int d = 0; d < 6; ++d) o[tt*6 + d] = f[base + d];
            }
        }
    }

    float4* op = out4 + (size_t)b * 3;
    op[0] = make_float4(o[0], o[1], o[2],  o[3]);
    op[1] = make_float4(o[4], o[5], o[6],  o[7]);
    op[2] = make_float4(o[8], o[9], o[10], o[11]);
}

extern "C" void kernel_launch(void* const* d_in, const int* in_sizes, int n_in,
                              void* d_out, int out_size, void* d_ws, size_t ws_size,
                              hipStream_t stream) {
    const float4* vt4   = (const float4*)d_in[0];
    const int*    vision = (const int*)d_in[1];
    float4*       out4  = (float4*)d_out;
    int B = in_sizes[1] / 5;   // vision is [B,5]

    int block = 256;
    int grid  = (B + block - 1) / block;
    belief_kernel<<<grid, block, 0, stream>>>(vt4, vision, out4, B);
}

// Round 2
// 51.173 us; speedup vs baseline: 1.2057x; 1.2057x over previous
//
#include <hip/hip_runtime.h>

// BeliefModuleOld: B=1e6, T=5, NTYPES=2, D=6
// in[0]: visible_treats [B,5,2,6] f32  (60 floats / batch = 15 float4)
// in[1]: vision         [B,5]     i32
// out:   [B,2,6] f32               (12 floats / batch = 3 float4)
//
// Coalesced version: each 256-thread block stages 256 batches' treats into
// LDS via global_load_lds (linear layout, coalesced), computes from LDS,
// stages the output tile in LDS (aliasing the treats buffer) and stores
// coalesced. Vision (6% of traffic) is loaded direct/strided.

#define WPB 256

__device__ __forceinline__ void gload_lds16(const void* g, void* l) {
    __builtin_amdgcn_global_load_lds(
        (const __attribute__((address_space(1))) void*)g,
        (__attribute__((address_space(3))) void*)l, 16, 0, 0);
}

__global__ __launch_bounds__(256) void belief_kernel(
    const float4* __restrict__ vt4,
    const int*    __restrict__ vision,
    float4*       __restrict__ out4,
    int B)
{
    __shared__ float4 s_vt[WPB * 15];   // 61440 B; reused as output stage

    const int tid  = threadIdx.x;
    const int lane = tid & 63;
    const int wave = tid >> 6;

    const int blockBase = blockIdx.x * WPB;          // first batch of block
    const int f4Total   = B * 15;
    const int f4Base    = blockBase * 15;

    // ---- stage treats: 3840 float4 per block, direct-to-LDS, coalesced ----
    // wave w, iter i stages float4 linear indices [i*256 + w*64, +64)
#pragma unroll
    for (int i = 0; i < 15; ++i) {
        const int l = i * 256 + wave * 64;           // wave-uniform LDS f4 idx
        int g = f4Base + l + lane;                   // per-lane global f4 idx
        if (g >= f4Total) g = f4Total - 1;           // clamp (tail block)
        gload_lds16(vt4 + g, &s_vt[l]);
    }

    // ---- vision: direct strided (only 20B/thread) ----
    const int b = blockBase + tid;
    int v[5] = {0, 0, 0, 0, 0};
    if (b < B) {
        const int* vp = vision + b * 5;
#pragma unroll
        for (int t = 0; t < 5; ++t) v[t] = vp[t];
    }

    __syncthreads();   // drains global_load_lds (vmcnt) + barrier

    // ---- compute: incremental scan over t, 3 ds_read_b128 per t ----
    float o[12];
#pragma unroll
    for (int tt = 0; tt < 2; ++tt) {
        o[tt*6+0]=0.f; o[tt*6+1]=0.f; o[tt*6+2]=0.f;
        o[tt*6+3]=0.f; o[tt*6+4]=0.f; o[tt*6+5]=1.f;
    }

    const int fbase = tid * 15;     // this thread's batch: float4 base in LDS
#pragma unroll
    for (int t = 0; t < 5; ++t) {
        float4 r0 = s_vt[fbase + t*3 + 0];   // tt0 d0..3
        float4 r1 = s_vt[fbase + t*3 + 1];   // tt0 d4,5 | tt1 d0,1
        float4 r2 = s_vt[fbase + t*3 + 2];   // tt1 d2..5

        // tt = 0
        {
            float m = fmaxf(fmaxf(fmaxf(r0.x, r0.y), fmaxf(r0.z, r0.w)), r1.x);
            bool valid = (v[t] != 0) && (m > 0.5f);
            if (valid) {
                o[0]=r0.x; o[1]=r0.y; o[2]=r0.z; o[3]=r0.w; o[4]=r1.x; o[5]=r1.y;
            }
        }
        // tt = 1
        {
            float m = fmaxf(fmaxf(fmaxf(r1.z, r1.w), fmaxf(r2.x, r2.y)), r2.z);
            bool valid = (v[t] != 0) && (m > 0.5f);
            if (valid) {
                o[6]=r1.z; o[7]=r1.w; o[8]=r2.x; o[9]=r2.y; o[10]=r2.z; o[11]=r2.w;
            }
        }
    }

    __syncthreads();   // all treats reads done before aliasing as out stage

    // ---- stage output tile (alias s_vt), then coalesced store ----
    float4* s_out = s_vt;                      // 768 float4 used
    s_out[tid*3 + 0] = make_float4(o[0], o[1], o[2],  o[3]);
    s_out[tid*3 + 1] = make_float4(o[4], o[5], o[6],  o[7]);
    s_out[tid*3 + 2] = make_float4(o[8], o[9], o[10], o[11]);

    __syncthreads();

    const int oTotal = B * 3;
    const int oBase  = blockBase * 3;
#pragma unroll
    for (int i = 0; i < 3; ++i) {
        const int l = i * 256 + tid;
        const int g = oBase + l;
        if (g < oTotal) out4[g] = s_out[l];
    }
}

extern "C" void kernel_launch(void* const* d_in, const int* in_sizes, int n_in,
                              void* d_out, int out_size, void* d_ws, size_t ws_size,
                              hipStream_t stream) {
    const float4* vt4    = (const float4*)d_in[0];
    const int*    vision = (const int*)d_in[1];
    float4*       out4   = (float4*)d_out;
    int B = in_sizes[1] / 5;   // vision is [B,5]

    int grid = (B + WPB - 1) / WPB;
    belief_kernel<<<grid, WPB, 0, stream>>>(vt4, vision, out4, B);
}